// Round 5
// baseline (583.454 us; speedup 1.0000x reference)
//
#include <hip/hip_runtime.h>
#include <cstdio>
#include <cstdint>

#define S_TOK 4096
#define CDIM  1024
#define EXP   8
#define HRAW  2744
#define HPAD  2816
#define MAXROWS  13312   // 104 tiles * 128
#define MAXTILES 104
#define NSLICE1  (HPAD / 128)   // 22
#define NSLICE2  (CDIM / 128)   // 8
#define NT1 (CDIM / 32)         // 32
#define NT2 (HPAD / 32)         // 88

typedef __attribute__((ext_vector_type(8))) short bf16x8;
typedef __attribute__((ext_vector_type(4))) float f32x4;
typedef __attribute__((ext_vector_type(4))) unsigned short us4;
typedef unsigned short us;

__device__ __forceinline__ us f2bf(float f) {
  unsigned u = __float_as_uint(f);
  u += 0x7fffu + ((u >> 16) & 1u);
  return (us)(u >> 16);
}

__device__ __forceinline__ void gl16(const us* g, us* l) {
  __builtin_amdgcn_global_load_lds((__attribute__((address_space(1))) void*)g,
                                   (__attribute__((address_space(3))) void*)l,
                                   16, 0, 0);
}

// bijective XCD swizzle (m204)
__device__ __forceinline__ int xcd_swz(int orig, int nwg) {
  int q = nwg >> 3, r = nwg & 7;
  int x = orig & 7, idx = orig >> 3;
  return (x < r ? x * (q + 1) : r * (q + 1) + (x - r) * q) + idx;
}

// ---------------- weight conversion (fp32 -> bf16, with padding) ----------------
__global__ void __launch_bounds__(256) cvt_rowpad(const float* __restrict__ src,
                                                  us* __restrict__ dst,
                                                  int nmat, int srows, int drows, int cols) {
  const int cpr = cols >> 2;
  const long total = (long)nmat * drows * cpr;
  for (long i = (long)blockIdx.x * blockDim.x + threadIdx.x; i < total;
       i += (long)gridDim.x * blockDim.x) {
    int c4 = (int)(i % cpr);
    long t = i / cpr;
    int r = (int)(t % drows);
    int m = (int)(t / drows);
    us4 o;
    if (r < srows) {
      float4 v = *(const float4*)(src + ((long)(m * srows + r) * cols + c4 * 4));
      o.x = f2bf(v.x); o.y = f2bf(v.y); o.z = f2bf(v.z); o.w = f2bf(v.w);
    } else {
      o.x = 0; o.y = 0; o.z = 0; o.w = 0;
    }
    *(us4*)(dst + ((long)(m * drows + r) * cols + c4 * 4)) = o;
  }
}

__global__ void __launch_bounds__(256) cvt_colpad(const float* __restrict__ src,
                                                  us* __restrict__ dst,
                                                  int rows, int scols, int dcols) {
  const int cpr = dcols >> 2;
  const long total = (long)rows * cpr;
  for (long i = (long)blockIdx.x * blockDim.x + threadIdx.x; i < total;
       i += (long)gridDim.x * blockDim.x) {
    int c4 = (int)(i % cpr);
    long r = i / cpr;
    int c = c4 * 4;
    us4 o;
    if (c < scols) {
      float4 v = *(const float4*)(src + r * (long)scols + c);
      o.x = f2bf(v.x); o.y = f2bf(v.y); o.z = f2bf(v.z); o.w = f2bf(v.w);
    } else {
      o.x = 0; o.y = 0; o.z = 0; o.w = 0;
    }
    *(us4*)(dst + r * (long)dcols + c) = o;
  }
}

// ---------------- gating (NO atomics) ----------------
__global__ void __launch_bounds__(256) gate_kernel(const float* __restrict__ x,
                                                   const float* __restrict__ gw,
                                                   us* __restrict__ xb,
                                                   int* __restrict__ tki,
                                                   float* __restrict__ tkw,
                                                   float* __restrict__ probs) {
  const int wv = threadIdx.x >> 6, lane = threadIdx.x & 63;
  const int s = blockIdx.x * 4 + wv;
  const float4* xs4 = (const float4*)(x + (size_t)s * CDIM);
  float acc[8] = {0, 0, 0, 0, 0, 0, 0, 0};
#pragma unroll
  for (int j = 0; j < 4; j++) {
    float4 v = xs4[lane * 4 + j];
    int c = lane * 16 + j * 4;
    us4 ov;
    ov.x = f2bf(v.x); ov.y = f2bf(v.y); ov.z = f2bf(v.z); ov.w = f2bf(v.w);
    *(us4*)(xb + (size_t)s * CDIM + c) = ov;
#pragma unroll
    for (int ee = 0; ee < 8; ee++) {
      const float* g = gw + ee * CDIM + c;
      acc[ee] += v.x * g[0] + v.y * g[1] + v.z * g[2] + v.w * g[3];
    }
  }
#pragma unroll
  for (int ee = 0; ee < 8; ee++) {
#pragma unroll
    for (int off = 32; off > 0; off >>= 1) acc[ee] += __shfl_xor(acc[ee], off, 64);
  }
  if (lane == 0) {
    float mx = acc[0];
    for (int ee = 1; ee < 8; ee++) mx = fmaxf(mx, acc[ee]);
    float p[8], sm = 0.f;
    for (int ee = 0; ee < 8; ee++) { p[ee] = expf(acc[ee] - mx); sm += p[ee]; }
    float inv = 1.f / sm;
    for (int ee = 0; ee < 8; ee++) probs[s * 8 + ee] = p[ee] * inv;
    int i0 = 0; float b0 = p[0];
    for (int ee = 1; ee < 8; ee++) if (p[ee] > b0) { b0 = p[ee]; i0 = ee; }
    int i1 = -1; float b1 = -1.f;
    for (int ee = 0; ee < 8; ee++) if (ee != i0 && p[ee] > b1) { b1 = p[ee]; i1 = ee; }
    float rw0 = b0 * inv, rw1 = b1 * inv;
    float den = 1.f / (rw0 + rw1);
    tki[2 * s] = i0; tki[2 * s + 1] = i1;
    tkw[2 * s] = rw0 * den; tkw[2 * s + 1] = rw1 * den;
  }
}

// ---------------- counting + routing lists + tiles + aux loss ----------------
__global__ void __launch_bounds__(512) build_kernel(const int* __restrict__ tki,
                                                    const float* __restrict__ tkw,
                                                    const float* __restrict__ probs,
                                                    int* __restrict__ meta,
                                                    int* __restrict__ pairtok,
                                                    float* __restrict__ pairw,
                                                    int* __restrict__ tile_expert,
                                                    float* __restrict__ aux_out) {
  const int tid = threadIdx.x, lane = tid & 63, wv = tid >> 6;
  __shared__ int s_cnt[EXP];
  __shared__ int s_amc[EXP];
  __shared__ float s_imp[EXP];
  {
    const int e = wv;
    int c_cnt = 0, c_amc = 0;
    float imp = 0.f;
    for (int s0 = 0; s0 < S_TOK; s0 += 64) {
      int s = s0 + lane;
      int i0 = tki[2 * s], i1 = tki[2 * s + 1];
      c_cnt += (i0 == e) || (i1 == e);
      c_amc += (i0 == e);
      imp += probs[s * 8 + e];
    }
#pragma unroll
    for (int off = 32; off > 0; off >>= 1) {
      c_cnt += __shfl_xor(c_cnt, off, 64);
      c_amc += __shfl_xor(c_amc, off, 64);
      imp   += __shfl_xor(imp, off, 64);
    }
    if (lane == 0) { s_cnt[e] = c_cnt; s_amc[e] = c_amc; s_imp[e] = imp; }
  }
  __syncthreads();
  int pad[EXP], start[EXP];
  int o = S_TOK;
#pragma unroll
  for (int j = 0; j < EXP; j++) {
    pad[j] = ((s_cnt[j] + 127) >> 7) << 7;
    start[j] = o;
    o += pad[j];
  }
  const int total = o;
  for (int r = tid; r < S_TOK; r += 512) { pairtok[r] = r; pairw[r] = 1.f; }
  {
    const int e = wv;
    int base = start[e];
    for (int s0 = 0; s0 < S_TOK; s0 += 64) {
      int s = s0 + lane;
      int i0 = tki[2 * s], i1 = tki[2 * s + 1];
      bool m0 = (i0 == e), m1 = (i1 == e);
      bool mm = m0 || m1;
      unsigned long long mk = __ballot(mm);
      if (mm) {
        int pos = base + __popcll(mk & ((1ull << lane) - 1ull));
        pairtok[pos] = s;
        pairw[pos] = m0 ? tkw[2 * s] : tkw[2 * s + 1];
      }
      base += __popcll(mk);
    }
    for (int r = base + lane; r < start[e] + pad[e]; r += 64) {
      pairtok[r] = -1; pairw[r] = 0.f;
    }
  }
  if (tid < 128) {
    int ex = 8;
    if (tid >= 32) {
      int rr = tid * 128;
#pragma unroll
      for (int j = 0; j < EXP; j++)
        if (rr >= start[j] && rr < start[j] + pad[j]) ex = j;
    }
    tile_expert[tid] = ex;
  }
  if (tid == 0) {
    meta[0] = total >> 7;
    float a = 0.f;
    for (int j = 0; j < EXP; j++)
      a += (s_imp[j] * (1.f / 4096.f)) * ((float)s_amc[j] * (1.f / 4096.f));
    aux_out[0] = 8.f * a;
  }
}

// ---------------- GEMM1: h = silu(x@w1^T) * (x@w2^T), bf16 out ----------------
// Double-buffered LDS, prefetch-before-compute (T3 minimum 2-phase): stage(t+1)
// issued before ds_read/MFMA of t; single barrier per K-step drains the prefetch
// after it has had the whole compute phase to fly.
__global__ void __launch_bounds__(256, 3) gemm1_kernel(
    const us* __restrict__ xb, const us* __restrict__ w1b, const us* __restrict__ w2b,
    const us* __restrict__ sw1b, const us* __restrict__ sw2b,
    const int* __restrict__ pairtok, const int* __restrict__ tile_expert,
    const int* __restrict__ meta, us* __restrict__ h) {
  const int wgid = xcd_swz(blockIdx.x, MAXTILES * NSLICE1);
  const int mt = wgid % MAXTILES;
  if (mt >= meta[0]) return;
  const int n0 = (wgid / MAXTILES) * 128;
  const int e = tile_expert[mt];
  const us* B1 = (e == 8) ? sw1b : (w1b + (size_t)e * HPAD * CDIM);
  const us* B2 = (e == 8) ? sw2b : (w2b + (size_t)e * HPAD * CDIM);
  const int row0 = mt * 128;
  __shared__ __align__(16) us sA[2][128 * 32];
  __shared__ __align__(16) us sB1[2][128 * 32];
  __shared__ __align__(16) us sB2[2][128 * 32];
  const int tid = threadIdx.x, lane = tid & 63;
  const int wm = tid >> 7, wn = (tid >> 6) & 1;
  const int sub = tid & 3, ra = tid >> 2;
  const int subx = sub ^ ((ra >> 1) & 3);     // inverse-swizzled global source chunk
  int t0 = pairtok[row0 + ra];      if (t0 < 0) t0 = 0;
  int t1 = pairtok[row0 + 64 + ra]; if (t1 < 0) t1 = 0;
  const us* gA0 = xb + (size_t)t0 * CDIM + subx * 8;
  const us* gA1 = xb + (size_t)t1 * CDIM + subx * 8;
  const us* gB1a = B1 + (size_t)(n0 + ra) * CDIM + subx * 8;
  const us* gB1b = B1 + (size_t)(n0 + 64 + ra) * CDIM + subx * 8;
  const us* gB2a = B2 + (size_t)(n0 + ra) * CDIM + subx * 8;
  const us* gB2b = B2 + (size_t)(n0 + 64 + ra) * CDIM + subx * 8;
  f32x4 au[4][4], av[4][4];
#pragma unroll
  for (int m = 0; m < 4; m++)
#pragma unroll
    for (int n = 0; n < 4; n++)
#pragma unroll
      for (int r = 0; r < 4; r++) { au[m][n][r] = 0.f; av[m][n][r] = 0.f; }

#define G1_STAGE(c, k0)                          \
  do {                                           \
    gl16(gA0 + (k0),  &sA[c][tid * 8]);          \
    gl16(gA1 + (k0),  &sA[c][(tid + 256) * 8]);  \
    gl16(gB1a + (k0), &sB1[c][tid * 8]);         \
    gl16(gB1b + (k0), &sB1[c][(tid + 256) * 8]); \
    gl16(gB2a + (k0), &sB2[c][tid * 8]);         \
    gl16(gB2b + (k0), &sB2[c][(tid + 256) * 8]); \
  } while (0)

  const int rl = lane & 15;
  const int kx = (((lane >> 4) ^ ((lane >> 1) & 3)) << 3);  // swizzled read slot
  G1_STAGE(0, 0);
  __syncthreads();
  for (int t = 0; t < NT1; t++) {
    const int cur = t & 1;
    if (t + 1 < NT1) G1_STAGE(cur ^ 1, (t + 1) * 32);
    bf16x8 a[4], b1[4], b2[4];
#pragma unroll
    for (int m = 0; m < 4; m++)
      a[m] = *(const bf16x8*)&sA[cur][(wm * 64 + m * 16 + rl) * 32 + kx];
#pragma unroll
    for (int n = 0; n < 4; n++) {
      b1[n] = *(const bf16x8*)&sB1[cur][(wn * 64 + n * 16 + rl) * 32 + kx];
      b2[n] = *(const bf16x8*)&sB2[cur][(wn * 64 + n * 16 + rl) * 32 + kx];
    }
#pragma unroll
    for (int m = 0; m < 4; m++)
#pragma unroll
      for (int n = 0; n < 4; n++) {
        au[m][n] = __builtin_amdgcn_mfma_f32_16x16x32_bf16(a[m], b1[n], au[m][n], 0, 0, 0);
        av[m][n] = __builtin_amdgcn_mfma_f32_16x16x32_bf16(a[m], b2[n], av[m][n], 0, 0, 0);
      }
    if (t + 1 < NT1) __syncthreads();
  }
#undef G1_STAGE
  const int rb = (lane >> 4) * 4, cb = lane & 15;
#pragma unroll
  for (int m = 0; m < 4; m++)
#pragma unroll
    for (int n = 0; n < 4; n++)
#pragma unroll
      for (int r = 0; r < 4; r++) {
        int row = row0 + wm * 64 + m * 16 + rb + r;
        int col = n0 + wn * 64 + n * 16 + cb;
        float u = au[m][n][r], v = av[m][n][r];
        float sg = 1.f / (1.f + __expf(-u));
        h[(size_t)row * HPAD + col] = f2bf(u * sg * v);
      }
}

// ---------------- GEMM2: out[tok] += w * (h @ w3^T) ----------------
__global__ void __launch_bounds__(256, 4) gemm2_kernel(
    const us* __restrict__ h, const us* __restrict__ w3b, const us* __restrict__ sw3b,
    const int* __restrict__ pairtok, const float* __restrict__ pairw,
    const int* __restrict__ tile_expert, const int* __restrict__ meta,
    float* __restrict__ out) {
  const int wgid = xcd_swz(blockIdx.x, MAXTILES * NSLICE2);
  const int mt = wgid % MAXTILES;
  if (mt >= meta[0]) return;
  const int n0 = (wgid / MAXTILES) * 128;
  const int e = tile_expert[mt];
  const us* B = (e == 8) ? sw3b : (w3b + (size_t)e * CDIM * HPAD);
  const int row0 = mt * 128;
  __shared__ __align__(16) us sA[2][128 * 32];
  __shared__ __align__(16) us sB[2][128 * 32];
  const int tid = threadIdx.x, lane = tid & 63;
  const int wm = tid >> 7, wn = (tid >> 6) & 1;
  const int sub = tid & 3, ra = tid >> 2;
  const int subx = sub ^ ((ra >> 1) & 3);
  const us* gA0 = h + (size_t)(row0 + ra) * HPAD + subx * 8;
  const us* gA1 = h + (size_t)(row0 + 64 + ra) * HPAD + subx * 8;
  const us* gB0 = B + (size_t)(n0 + ra) * HPAD + subx * 8;
  const us* gB1 = B + (size_t)(n0 + 64 + ra) * HPAD + subx * 8;
  f32x4 ac[4][4];
#pragma unroll
  for (int m = 0; m < 4; m++)
#pragma unroll
    for (int n = 0; n < 4; n++)
#pragma unroll
      for (int r = 0; r < 4; r++) ac[m][n][r] = 0.f;

#define G2_STAGE(c, k0)                          \
  do {                                           \
    gl16(gA0 + (k0), &sA[c][tid * 8]);           \
    gl16(gA1 + (k0), &sA[c][(tid + 256) * 8]);   \
    gl16(gB0 + (k0), &sB[c][tid * 8]);           \
    gl16(gB1 + (k0), &sB[c][(tid + 256) * 8]);   \
  } while (0)

  const int rl = lane & 15;
  const int kx = (((lane >> 4) ^ ((lane >> 1) & 3)) << 3);
  G2_STAGE(0, 0);
  __syncthreads();
  for (int t = 0; t < NT2; t++) {
    const int cur = t & 1;
    if (t + 1 < NT2) G2_STAGE(cur ^ 1, (t + 1) * 32);
    bf16x8 a[4], b[4];
#pragma unroll
    for (int m = 0; m < 4; m++)
      a[m] = *(const bf16x8*)&sA[cur][(wm * 64 + m * 16 + rl) * 32 + kx];
#pragma unroll
    for (int n = 0; n < 4; n++)
      b[n] = *(const bf16x8*)&sB[cur][(wn * 64 + n * 16 + rl) * 32 + kx];
#pragma unroll
    for (int m = 0; m < 4; m++)
#pragma unroll
      for (int n = 0; n < 4; n++)
        ac[m][n] = __builtin_amdgcn_mfma_f32_16x16x32_bf16(a[m], b[n], ac[m][n], 0, 0, 0);
    if (t + 1 < NT2) __syncthreads();
  }
#undef G2_STAGE
  const int rb = (lane >> 4) * 4, cb = lane & 15;
  int toks[4][4]; float wts[4][4];
#pragma unroll
  for (int m = 0; m < 4; m++)
#pragma unroll
    for (int r = 0; r < 4; r++) {
      int row = row0 + wm * 64 + m * 16 + rb + r;
      toks[m][r] = pairtok[row];
      wts[m][r] = pairw[row];
    }
#pragma unroll
  for (int m = 0; m < 4; m++)
#pragma unroll
    for (int n = 0; n < 4; n++)
#pragma unroll
      for (int r = 0; r < 4; r++) {
        if (toks[m][r] >= 0) {
          int col = n0 + wn * 64 + n * 16 + cb;
          atomicAdd(&out[(size_t)toks[m][r] * CDIM + col], ac[m][n][r] * wts[m][r]);
        }
      }
}

extern "C" void kernel_launch(void* const* d_in, const int* in_sizes, int n_in,
                              void* d_out, int out_size, void* d_ws, size_t ws_size,
                              hipStream_t stream) {
  const float* x   = (const float*)d_in[0];
  const float* gw  = (const float*)d_in[1];
  const float* w1  = (const float*)d_in[2];
  const float* w2  = (const float*)d_in[3];
  const float* w3  = (const float*)d_in[4];
  const float* sw1 = (const float*)d_in[5];
  const float* sw2 = (const float*)d_in[6];
  const float* sw3 = (const float*)d_in[7];
  float* out = (float*)d_out;
  char* ws = (char*)d_ws;
  size_t off = 0;
  auto take = [&](size_t bytes) -> char* {
    char* p = ws + off;
    off = (off + bytes + 255) & ~(size_t)255;
    return p;
  };
  us* xb    = (us*)take((size_t)S_TOK * CDIM * 2);
  us* w1b   = (us*)take((size_t)EXP * HPAD * CDIM * 2);
  us* w2b   = (us*)take((size_t)EXP * HPAD * CDIM * 2);
  us* w3b   = (us*)take((size_t)EXP * CDIM * HPAD * 2);
  us* sw1b  = (us*)take((size_t)HPAD * CDIM * 2);
  us* sw2b  = (us*)take((size_t)HPAD * CDIM * 2);
  us* sw3b  = (us*)take((size_t)CDIM * HPAD * 2);
  us* hbuf  = (us*)take((size_t)MAXROWS * HPAD * 2);
  int* pairtok = (int*)take(MAXROWS * 4);
  float* pairw = (float*)take(MAXROWS * 4);
  int* tile_expert = (int*)take(128 * 4);
  int* tki = (int*)take(S_TOK * 2 * 4);
  float* tkw = (float*)take(S_TOK * 2 * 4);
  float* probs = (float*)take(S_TOK * EXP * 4);
  int* meta = (int*)take(256);
  if (off > ws_size) {
    fprintf(stderr, "MoE kernel: ws too small, need %zu got %zu\n", off, ws_size);
    return;
  }
  hipMemsetAsync(d_out, 0, (size_t)out_size * sizeof(float), stream);
  cvt_rowpad<<<4096, 256, 0, stream>>>(w1, w1b, 8, HRAW, HPAD, CDIM);
  cvt_rowpad<<<4096, 256, 0, stream>>>(w2, w2b, 8, HRAW, HPAD, CDIM);
  cvt_colpad<<<4096, 256, 0, stream>>>(w3, w3b, EXP * CDIM, HRAW, HPAD);
  cvt_rowpad<<<1024, 256, 0, stream>>>(sw1, sw1b, 1, HRAW, HPAD, CDIM);
  cvt_rowpad<<<1024, 256, 0, stream>>>(sw2, sw2b, 1, HRAW, HPAD, CDIM);
  cvt_colpad<<<1024, 256, 0, stream>>>(sw3, sw3b, CDIM, HRAW, HPAD);
  gate_kernel<<<S_TOK / 4, 256, 0, stream>>>(x, gw, xb, tki, tkw, probs);
  build_kernel<<<1, 512, 0, stream>>>(tki, tkw, probs, meta, pairtok, pairw, tile_expert,
                                      out + (size_t)S_TOK * CDIM);
  gemm1_kernel<<<MAXTILES * NSLICE1, 256, 0, stream>>>(
      xb, w1b, w2b, sw1b, sw2b, pairtok, tile_expert, meta, hbuf);
  gemm2_kernel<<<MAXTILES * NSLICE2, 256, 0, stream>>>(
      hbuf, w3b, sw3b, pairtok, pairw, tile_expert, meta, out);
}

// Round 6
// 470.635 us; speedup vs baseline: 1.2397x; 1.2397x over previous
//
#include <hip/hip_runtime.h>
#include <cstdio>
#include <cstdint>

#define S_TOK 4096
#define CDIM  1024
#define EXP   8
#define HRAW  2744
#define HPAD  2816
#define MAXROWS  13312   // 104 tiles * 128
#define MAXTILES 104
#define NSLICE1  (HPAD / 128)   // 22
#define NSLICE2  (CDIM / 128)   // 8

typedef __attribute__((ext_vector_type(8))) short bf16x8;
typedef __attribute__((ext_vector_type(4))) float f32x4;
typedef __attribute__((ext_vector_type(4))) unsigned short us4;
typedef unsigned short us;

__device__ __forceinline__ us f2bf(float f) {
  unsigned u = __float_as_uint(f);
  u += 0x7fffu + ((u >> 16) & 1u);
  return (us)(u >> 16);
}

__device__ __forceinline__ void gl16(const us* g, us* l) {
  __builtin_amdgcn_global_load_lds((__attribute__((address_space(1))) void*)g,
                                   (__attribute__((address_space(3))) void*)l,
                                   16, 0, 0);
}

// bijective XCD swizzle (m204)
__device__ __forceinline__ int xcd_swz(int orig, int nwg) {
  int q = nwg >> 3, r = nwg & 7;
  int x = orig & 7, idx = orig >> 3;
  return (x < r ? x * (q + 1) : r * (q + 1) + (x - r) * q) + idx;
}

// ---------------- fused weight conversion (fp32 -> bf16, padded) ----------------
// One launch for all 6 tensors. All region sizes compile-time; grid-stride over
// 4-element dst chunks. rowpad: [nmat][2744->2816][1024]; colpad: [rows][2744->2816].
#define CH_RP1  (HPAD * CDIM / 4)          // 720896 chunks per rowpad matrix
#define CH_CPR  (HPAD / 4)                 // 704 chunks per colpad row
#define R_W1    (8 * CH_RP1)               // 5767168
#define R_W2    (R_W1 + 8 * CH_RP1)        // 11534336
#define R_W3    (R_W2 + 8 * CDIM * CH_CPR) // 17301504
#define R_SW1   (R_W3 + CH_RP1)            // 18022400
#define R_SW2   (R_SW1 + CH_RP1)           // 18743296
#define R_SW3   (R_SW2 + CDIM * CH_CPR)    // 19464192

__device__ __forceinline__ void cvt4_rowpad(const float* __restrict__ src,
                                            us* __restrict__ dst, int idx) {
  int m = idx / CH_RP1, rem = idx - m * CH_RP1;
  int r = rem >> 8, c4 = rem & 255;   // 1024/4 = 256 chunks/row
  us4 o;
  if (r < HRAW) {
    float4 v = *(const float4*)(src + ((size_t)(m * HRAW + r) * CDIM + c4 * 4));
    o.x = f2bf(v.x); o.y = f2bf(v.y); o.z = f2bf(v.z); o.w = f2bf(v.w);
  } else { o.x = 0; o.y = 0; o.z = 0; o.w = 0; }
  *(us4*)(dst + ((size_t)(m * HPAD + r) * CDIM + c4 * 4)) = o;
}

__device__ __forceinline__ void cvt4_colpad(const float* __restrict__ src,
                                            us* __restrict__ dst, int idx) {
  int r = idx / CH_CPR, c4 = idx - r * CH_CPR;
  int c = c4 * 4;
  us4 o;
  if (c < HRAW) {   // HRAW%4==0 -> chunk fully valid or fully pad
    float4 v = *(const float4*)(src + (size_t)r * HRAW + c);
    o.x = f2bf(v.x); o.y = f2bf(v.y); o.z = f2bf(v.z); o.w = f2bf(v.w);
  } else { o.x = 0; o.y = 0; o.z = 0; o.w = 0; }
  *(us4*)(dst + (size_t)r * HPAD + c) = o;
}

__global__ void __launch_bounds__(256) cvt_all_kernel(
    const float* __restrict__ w1, const float* __restrict__ w2,
    const float* __restrict__ w3, const float* __restrict__ sw1,
    const float* __restrict__ sw2, const float* __restrict__ sw3,
    us* __restrict__ w1b, us* __restrict__ w2b, us* __restrict__ w3b,
    us* __restrict__ sw1b, us* __restrict__ sw2b, us* __restrict__ sw3b) {
  for (int i = blockIdx.x * 256 + threadIdx.x; i < R_SW3; i += gridDim.x * 256) {
    if (i < R_W1)       cvt4_rowpad(w1,  w1b,  i);
    else if (i < R_W2)  cvt4_rowpad(w2,  w2b,  i - R_W1);
    else if (i < R_W3)  cvt4_colpad(w3,  w3b,  i - R_W2);
    else if (i < R_SW1) cvt4_rowpad(sw1, sw1b, i - R_W3);
    else if (i < R_SW2) cvt4_rowpad(sw2, sw2b, i - R_SW1);
    else                cvt4_colpad(sw3, sw3b, i - R_SW2);
  }
}

// ---------------- gating (NO atomics) ----------------
__global__ void __launch_bounds__(256) gate_kernel(const float* __restrict__ x,
                                                   const float* __restrict__ gw,
                                                   us* __restrict__ xb,
                                                   int* __restrict__ tki,
                                                   float* __restrict__ tkw,
                                                   float* __restrict__ probs) {
  const int wv = threadIdx.x >> 6, lane = threadIdx.x & 63;
  const int s = blockIdx.x * 4 + wv;
  const float4* xs4 = (const float4*)(x + (size_t)s * CDIM);
  float acc[8] = {0, 0, 0, 0, 0, 0, 0, 0};
#pragma unroll
  for (int j = 0; j < 4; j++) {
    float4 v = xs4[lane * 4 + j];
    int c = lane * 16 + j * 4;
    us4 ov;
    ov.x = f2bf(v.x); ov.y = f2bf(v.y); ov.z = f2bf(v.z); ov.w = f2bf(v.w);
    *(us4*)(xb + (size_t)s * CDIM + c) = ov;
#pragma unroll
    for (int ee = 0; ee < 8; ee++) {
      const float* g = gw + ee * CDIM + c;
      acc[ee] += v.x * g[0] + v.y * g[1] + v.z * g[2] + v.w * g[3];
    }
  }
#pragma unroll
  for (int ee = 0; ee < 8; ee++) {
#pragma unroll
    for (int off = 32; off > 0; off >>= 1) acc[ee] += __shfl_xor(acc[ee], off, 64);
  }
  if (lane == 0) {
    float mx = acc[0];
    for (int ee = 1; ee < 8; ee++) mx = fmaxf(mx, acc[ee]);
    float p[8], sm = 0.f;
    for (int ee = 0; ee < 8; ee++) { p[ee] = expf(acc[ee] - mx); sm += p[ee]; }
    float inv = 1.f / sm;
    for (int ee = 0; ee < 8; ee++) probs[s * 8 + ee] = p[ee] * inv;
    int i0 = 0; float b0 = p[0];
    for (int ee = 1; ee < 8; ee++) if (p[ee] > b0) { b0 = p[ee]; i0 = ee; }
    int i1 = -1; float b1 = -1.f;
    for (int ee = 0; ee < 8; ee++) if (ee != i0 && p[ee] > b1) { b1 = p[ee]; i1 = ee; }
    float rw0 = b0 * inv, rw1 = b1 * inv;
    float den = 1.f / (rw0 + rw1);
    tki[2 * s] = i0; tki[2 * s + 1] = i1;
    tkw[2 * s] = rw0 * den; tkw[2 * s + 1] = rw1 * den;
  }
}

// ---------------- counting + routing lists + inverse map + aux loss ----------------
__global__ void __launch_bounds__(512) build_kernel(const int* __restrict__ tki,
                                                    const float* __restrict__ tkw,
                                                    const float* __restrict__ probs,
                                                    int* __restrict__ meta,
                                                    int* __restrict__ pairtok,
                                                    float* __restrict__ pairw,
                                                    int* __restrict__ invmap,
                                                    int* __restrict__ tile_expert,
                                                    float* __restrict__ aux_out) {
  const int tid = threadIdx.x, lane = tid & 63, wv = tid >> 6;
  __shared__ int s_cnt[EXP];
  __shared__ int s_amc[EXP];
  __shared__ float s_imp[EXP];
  {
    const int e = wv;
    int c_cnt = 0, c_amc = 0;
    float imp = 0.f;
    for (int s0 = 0; s0 < S_TOK; s0 += 64) {
      int s = s0 + lane;
      int i0 = tki[2 * s], i1 = tki[2 * s + 1];
      c_cnt += (i0 == e) || (i1 == e);
      c_amc += (i0 == e);
      imp += probs[s * 8 + e];
    }
#pragma unroll
    for (int off = 32; off > 0; off >>= 1) {
      c_cnt += __shfl_xor(c_cnt, off, 64);
      c_amc += __shfl_xor(c_amc, off, 64);
      imp   += __shfl_xor(imp, off, 64);
    }
    if (lane == 0) { s_cnt[e] = c_cnt; s_amc[e] = c_amc; s_imp[e] = imp; }
  }
  __syncthreads();
  int pad[EXP], start[EXP];
  int o = S_TOK;
#pragma unroll
  for (int j = 0; j < EXP; j++) {
    pad[j] = ((s_cnt[j] + 127) >> 7) << 7;
    start[j] = o;
    o += pad[j];
  }
  const int total = o;
  for (int r = tid; r < S_TOK; r += 512) { pairtok[r] = r; pairw[r] = 1.f; }
  {
    const int e = wv;
    int base = start[e];
    for (int s0 = 0; s0 < S_TOK; s0 += 64) {
      int s = s0 + lane;
      int i0 = tki[2 * s], i1 = tki[2 * s + 1];
      bool m0 = (i0 == e), m1 = (i1 == e);
      bool mm = m0 || m1;
      unsigned long long mk = __ballot(mm);
      if (mm) {
        int pos = base + __popcll(mk & ((1ull << lane) - 1ull));
        pairtok[pos] = s;
        pairw[pos] = m0 ? tkw[2 * s] : tkw[2 * s + 1];
        invmap[2 * s + (m0 ? 0 : 1)] = pos;
      }
      base += __popcll(mk);
    }
    for (int r = base + lane; r < start[e] + pad[e]; r += 64) {
      pairtok[r] = -1; pairw[r] = 0.f;
    }
  }
  if (tid < 128) {
    int ex = 8;
    if (tid >= 32) {
      int rr = tid * 128;
#pragma unroll
      for (int j = 0; j < EXP; j++)
        if (rr >= start[j] && rr < start[j] + pad[j]) ex = j;
    }
    tile_expert[tid] = ex;
  }
  if (tid == 0) {
    meta[0] = total >> 7;
    float a = 0.f;
    for (int j = 0; j < EXP; j++)
      a += (s_imp[j] * (1.f / 4096.f)) * ((float)s_amc[j] * (1.f / 4096.f));
    aux_out[0] = 8.f * a;
  }
}

// ---------------- GEMM1: h = silu(x@w1^T) * (x@w2^T), bf16 out ----------------
// Round-4 structure (single-buffer; verified 0 bank conflicts via chunk swizzle).
__global__ void __launch_bounds__(256, 2) gemm1_kernel(
    const us* __restrict__ xb, const us* __restrict__ w1b, const us* __restrict__ w2b,
    const us* __restrict__ sw1b, const us* __restrict__ sw2b,
    const int* __restrict__ pairtok, const int* __restrict__ tile_expert,
    const int* __restrict__ meta, us* __restrict__ h) {
  const int wgid = xcd_swz(blockIdx.x, MAXTILES * NSLICE1);
  const int mt = wgid % MAXTILES;
  if (mt >= meta[0]) return;
  const int n0 = (wgid / MAXTILES) * 128;
  const int e = tile_expert[mt];
  const us* B1 = (e == 8) ? sw1b : (w1b + (size_t)e * HPAD * CDIM);
  const us* B2 = (e == 8) ? sw2b : (w2b + (size_t)e * HPAD * CDIM);
  const int row0 = mt * 128;
  __shared__ __align__(16) us sA[128 * 32];
  __shared__ __align__(16) us sB1[128 * 32];
  __shared__ __align__(16) us sB2[128 * 32];
  const int tid = threadIdx.x, lane = tid & 63;
  const int wm = tid >> 7, wn = (tid >> 6) & 1;
  const int sub = tid & 3, ra = tid >> 2;
  const int subx = sub ^ ((ra >> 1) & 3);     // inverse-swizzled global source chunk
  int t0 = pairtok[row0 + ra];      if (t0 < 0) t0 = 0;
  int t1 = pairtok[row0 + 64 + ra]; if (t1 < 0) t1 = 0;
  const us* gA0 = xb + (size_t)t0 * CDIM + subx * 8;
  const us* gA1 = xb + (size_t)t1 * CDIM + subx * 8;
  const us* gB1a = B1 + (size_t)(n0 + ra) * CDIM + subx * 8;
  const us* gB1b = B1 + (size_t)(n0 + 64 + ra) * CDIM + subx * 8;
  const us* gB2a = B2 + (size_t)(n0 + ra) * CDIM + subx * 8;
  const us* gB2b = B2 + (size_t)(n0 + 64 + ra) * CDIM + subx * 8;
  f32x4 au[4][4], av[4][4];
#pragma unroll
  for (int m = 0; m < 4; m++)
#pragma unroll
    for (int n = 0; n < 4; n++)
#pragma unroll
      for (int r = 0; r < 4; r++) { au[m][n][r] = 0.f; av[m][n][r] = 0.f; }

  const int rl = lane & 15;
  const int kx = (((lane >> 4) ^ ((lane >> 1) & 3)) << 3);  // swizzled read slot
  for (int k0 = 0; k0 < CDIM; k0 += 32) {
    gl16(gA0 + k0,  &sA[tid * 8]);
    gl16(gA1 + k0,  &sA[(tid + 256) * 8]);
    gl16(gB1a + k0, &sB1[tid * 8]);
    gl16(gB1b + k0, &sB1[(tid + 256) * 8]);
    gl16(gB2a + k0, &sB2[tid * 8]);
    gl16(gB2b + k0, &sB2[(tid + 256) * 8]);
    __syncthreads();
    bf16x8 a[4], b1[4], b2[4];
#pragma unroll
    for (int m = 0; m < 4; m++)
      a[m] = *(const bf16x8*)&sA[(wm * 64 + m * 16 + rl) * 32 + kx];
#pragma unroll
    for (int n = 0; n < 4; n++) {
      b1[n] = *(const bf16x8*)&sB1[(wn * 64 + n * 16 + rl) * 32 + kx];
      b2[n] = *(const bf16x8*)&sB2[(wn * 64 + n * 16 + rl) * 32 + kx];
    }
#pragma unroll
    for (int m = 0; m < 4; m++)
#pragma unroll
      for (int n = 0; n < 4; n++) {
        au[m][n] = __builtin_amdgcn_mfma_f32_16x16x32_bf16(a[m], b1[n], au[m][n], 0, 0, 0);
        av[m][n] = __builtin_amdgcn_mfma_f32_16x16x32_bf16(a[m], b2[n], av[m][n], 0, 0, 0);
      }
    __syncthreads();
  }
  const int rb = (lane >> 4) * 4, cb = lane & 15;
#pragma unroll
  for (int m = 0; m < 4; m++)
#pragma unroll
    for (int n = 0; n < 4; n++)
#pragma unroll
      for (int r = 0; r < 4; r++) {
        int row = row0 + wm * 64 + m * 16 + rb + r;
        int col = n0 + wn * 64 + n * 16 + cb;
        float u = au[m][n][r], v = av[m][n][r];
        float sg = 1.f / (1.f + __expf(-u));
        h[(size_t)row * HPAD + col] = f2bf(u * sg * v);
      }
}

// ---------------- GEMM2: eo[slot] = h @ w3^T (plain stores, no atomics) -------
__global__ void __launch_bounds__(256, 2) gemm2_kernel(
    const us* __restrict__ h, const us* __restrict__ w3b, const us* __restrict__ sw3b,
    const int* __restrict__ tile_expert, const int* __restrict__ meta,
    float* __restrict__ eo) {
  const int wgid = xcd_swz(blockIdx.x, MAXTILES * NSLICE2);
  const int mt = wgid % MAXTILES;
  if (mt >= meta[0]) return;
  const int n0 = (wgid / MAXTILES) * 128;
  const int e = tile_expert[mt];
  const us* B = (e == 8) ? sw3b : (w3b + (size_t)e * CDIM * HPAD);
  const int row0 = mt * 128;
  __shared__ __align__(16) us sA[128 * 32];
  __shared__ __align__(16) us sB[128 * 32];
  const int tid = threadIdx.x, lane = tid & 63;
  const int wm = tid >> 7, wn = (tid >> 6) & 1;
  const int sub = tid & 3, ra = tid >> 2;
  const int subx = sub ^ ((ra >> 1) & 3);
  const us* gA0 = h + (size_t)(row0 + ra) * HPAD + subx * 8;
  const us* gA1 = h + (size_t)(row0 + 64 + ra) * HPAD + subx * 8;
  const us* gB0 = B + (size_t)(n0 + ra) * HPAD + subx * 8;
  const us* gB1 = B + (size_t)(n0 + 64 + ra) * HPAD + subx * 8;
  f32x4 ac[4][4];
#pragma unroll
  for (int m = 0; m < 4; m++)
#pragma unroll
    for (int n = 0; n < 4; n++)
#pragma unroll
      for (int r = 0; r < 4; r++) ac[m][n][r] = 0.f;

  const int rl = lane & 15;
  const int kx = (((lane >> 4) ^ ((lane >> 1) & 3)) << 3);
  for (int k0 = 0; k0 < HPAD; k0 += 32) {
    gl16(gA0 + k0, &sA[tid * 8]);
    gl16(gA1 + k0, &sA[(tid + 256) * 8]);
    gl16(gB0 + k0, &sB[tid * 8]);
    gl16(gB1 + k0, &sB[(tid + 256) * 8]);
    __syncthreads();
    bf16x8 a[4], b[4];
#pragma unroll
    for (int m = 0; m < 4; m++)
      a[m] = *(const bf16x8*)&sA[(wm * 64 + m * 16 + rl) * 32 + kx];
#pragma unroll
    for (int n = 0; n < 4; n++)
      b[n] = *(const bf16x8*)&sB[(wn * 64 + n * 16 + rl) * 32 + kx];
#pragma unroll
    for (int m = 0; m < 4; m++)
#pragma unroll
      for (int n = 0; n < 4; n++)
        ac[m][n] = __builtin_amdgcn_mfma_f32_16x16x32_bf16(a[m], b[n], ac[m][n], 0, 0, 0);
    __syncthreads();
  }
  const int rb = (lane >> 4) * 4, cb = lane & 15;
#pragma unroll
  for (int m = 0; m < 4; m++)
#pragma unroll
    for (int n = 0; n < 4; n++)
#pragma unroll
      for (int r = 0; r < 4; r++) {
        int row = row0 + wm * 64 + m * 16 + rb + r;
        int col = n0 + wn * 64 + n * 16 + cb;
        eo[(size_t)row * CDIM + col] = ac[m][n][r];
      }
}

// ---------------- combine: out[tok] = eo[tok] + w0*eo[slot0] + w1*eo[slot1] ----
__global__ void __launch_bounds__(256) combine_kernel(const float* __restrict__ eo,
                                                      const int* __restrict__ invmap,
                                                      const float* __restrict__ pairw,
                                                      float* __restrict__ out) {
  const int s = blockIdx.x;
  const int c = threadIdx.x * 4;
  const int j0 = invmap[2 * s], j1 = invmap[2 * s + 1];
  const float w0 = pairw[j0], w1 = pairw[j1];
  float4 a = *(const float4*)(eo + (size_t)s * CDIM + c);
  float4 b = *(const float4*)(eo + (size_t)j0 * CDIM + c);
  float4 d = *(const float4*)(eo + (size_t)j1 * CDIM + c);
  float4 o;
  o.x = a.x + w0 * b.x + w1 * d.x;
  o.y = a.y + w0 * b.y + w1 * d.y;
  o.z = a.z + w0 * b.z + w1 * d.z;
  o.w = a.w + w0 * b.w + w1 * d.w;
  *(float4*)(out + (size_t)s * CDIM + c) = o;
}

extern "C" void kernel_launch(void* const* d_in, const int* in_sizes, int n_in,
                              void* d_out, int out_size, void* d_ws, size_t ws_size,
                              hipStream_t stream) {
  const float* x   = (const float*)d_in[0];
  const float* gw  = (const float*)d_in[1];
  const float* w1  = (const float*)d_in[2];
  const float* w2  = (const float*)d_in[3];
  const float* w3  = (const float*)d_in[4];
  const float* sw1 = (const float*)d_in[5];
  const float* sw2 = (const float*)d_in[6];
  const float* sw3 = (const float*)d_in[7];
  float* out = (float*)d_out;
  char* ws = (char*)d_ws;
  size_t off = 0;
  auto take = [&](size_t bytes) -> char* {
    char* p = ws + off;
    off = (off + bytes + 255) & ~(size_t)255;
    return p;
  };
  us* xb    = (us*)take((size_t)S_TOK * CDIM * 2);
  us* w1b   = (us*)take((size_t)EXP * HPAD * CDIM * 2);
  us* w2b   = (us*)take((size_t)EXP * HPAD * CDIM * 2);
  us* w3b   = (us*)take((size_t)EXP * CDIM * HPAD * 2);
  us* sw1b  = (us*)take((size_t)HPAD * CDIM * 2);
  us* sw2b  = (us*)take((size_t)HPAD * CDIM * 2);
  us* sw3b  = (us*)take((size_t)CDIM * HPAD * 2);
  us* hbuf  = (us*)take((size_t)MAXROWS * HPAD * 2);
  int* pairtok = (int*)take(MAXROWS * 4);
  float* pairw = (float*)take(MAXROWS * 4);
  int* invmap  = (int*)take(S_TOK * 2 * 4);
  int* tile_expert = (int*)take(128 * 4);
  int* tki = (int*)take(S_TOK * 2 * 4);
  float* tkw = (float*)take(S_TOK * 2 * 4);
  float* probs = (float*)take(S_TOK * EXP * 4);
  int* meta = (int*)take(256);
  // eo (fp32, 13312x1024 = 54.5 MB) aliases w1b+w2b (92 MB) — both dead after gemm1.
  float* eo = (float*)w1b;
  if (off > ws_size) {
    fprintf(stderr, "MoE kernel: ws too small, need %zu got %zu\n", off, ws_size);
    return;
  }
  cvt_all_kernel<<<2048, 256, 0, stream>>>(w1, w2, w3, sw1, sw2, sw3,
                                           w1b, w2b, w3b, sw1b, sw2b, sw3b);
  gate_kernel<<<S_TOK / 4, 256, 0, stream>>>(x, gw, xb, tki, tkw, probs);
  build_kernel<<<1, 512, 0, stream>>>(tki, tkw, probs, meta, pairtok, pairw, invmap,
                                      tile_expert, out + (size_t)S_TOK * CDIM);
  gemm1_kernel<<<MAXTILES * NSLICE1, 256, 0, stream>>>(
      xb, w1b, w2b, sw1b, sw2b, pairtok, tile_expert, meta, hbuf);
  gemm2_kernel<<<MAXTILES * NSLICE2, 256, 0, stream>>>(
      hbuf, w3b, sw3b, tile_expert, meta, eo);
  combine_kernel<<<S_TOK, 256, 0, stream>>>(eo, invmap, pairw, out);
}